// Round 1
// baseline (564.194 us; speedup 1.0000x reference)
//
#include <hip/hip_runtime.h>

#define INPUT 32
#define HIDDEN 64
#define BATCH 4096
#define SEQ 256

__device__ __forceinline__ float readlane_f(float v, int l) {
    return __uint_as_float(__builtin_amdgcn_readlane(__float_as_uint(v), l));
}

// One wave (64 lanes) per batch chain. Lane j owns hidden unit j:
//   - W_hh row j (64 VGPRs) and W_ih row j (32 VGPRs) register-resident
//   - h[j] in one VGPR; broadcast of h[k] via v_readlane -> SGPR -> v_fmac
//   - x[b,t,:] is wave-uniform -> scalar loads (SMEM pipe), SGPR FMA operand
// __launch_bounds__(256,4): cap VGPRs at 128 so 4 waves/SIMD stay resident.
__global__ __launch_bounds__(256, 4) void rnn_fused_kernel(
    const float* __restrict__ x,     // [B, T, 32]
    const float* __restrict__ W_ih,  // [64, 32]
    const float* __restrict__ W_hh,  // [64, 64]
    const float* __restrict__ b_ih,  // [64]
    const float* __restrict__ b_hh,  // [64]
    const float* __restrict__ W_fc,  // [1, 64]
    const float* __restrict__ b_fc,  // [1]
    float* __restrict__ out)         // [B, 1]
{
    const int lane = threadIdx.x & 63;
    int b = blockIdx.x * 4 + (threadIdx.x >> 6);
    // Force wave-uniformity so x addressing scalarizes to s_load.
    b = __builtin_amdgcn_readfirstlane(b);

    // Per-lane weight rows (tiny: whole W_hh/W_ih stay hot in L2).
    float whh[HIDDEN];
#pragma unroll
    for (int k = 0; k < HIDDEN; ++k) whh[k] = W_hh[lane * HIDDEN + k];
    float wih[INPUT];
#pragma unroll
    for (int i = 0; i < INPUT; ++i) wih[i] = W_ih[lane * INPUT + i];
    const float bias = b_ih[lane] + b_hh[lane];

    const float* __restrict__ xb = x + (size_t)b * SEQ * INPUT;

    float h = 0.0f;

#pragma unroll 2
    for (int t = 0; t < SEQ; ++t) {
        const float* __restrict__ xt = xb + t * INPUT;  // uniform pointer

        // Input projection: x values are wave-uniform scalars (SMEM loads).
        float a0 = bias, a1 = 0.0f, a2 = 0.0f, a3 = 0.0f;
#pragma unroll
        for (int i = 0; i < INPUT; i += 4) {
            a0 = fmaf(wih[i + 0], xt[i + 0], a0);
            a1 = fmaf(wih[i + 1], xt[i + 1], a1);
            a2 = fmaf(wih[i + 2], xt[i + 2], a2);
            a3 = fmaf(wih[i + 3], xt[i + 3], a3);
        }

        // Recurrent matvec: broadcast h[k] via readlane (VALU pipe, no LDS).
        // t==0 has h==0 so this is a harmless no-op pass (keeps control uniform).
#pragma unroll
        for (int k = 0; k < HIDDEN; k += 4) {
            a0 = fmaf(whh[k + 0], readlane_f(h, k + 0), a0);
            a1 = fmaf(whh[k + 1], readlane_f(h, k + 1), a1);
            a2 = fmaf(whh[k + 2], readlane_f(h, k + 2), a2);
            a3 = fmaf(whh[k + 3], readlane_f(h, k + 3), a3);
        }

        float pre = (a0 + a1) + (a2 + a3);
        // tanh(p) = 1 - 2/(exp(2p)+1); saturates correctly for |p| large.
        float e = __expf(2.0f * pre);
        h = 1.0f - 2.0f * __builtin_amdgcn_rcpf(e + 1.0f);
    }

    // Head: out[b] = sum_j h[j]*W_fc[j] + b_fc (wave reduction, once per chain).
    float v = h * W_fc[lane];
#pragma unroll
    for (int off = 32; off > 0; off >>= 1) v += __shfl_xor(v, off, 64);
    if (lane == 0) out[b] = v + b_fc[0];
}

extern "C" void kernel_launch(void* const* d_in, const int* in_sizes, int n_in,
                              void* d_out, int out_size, void* d_ws, size_t ws_size,
                              hipStream_t stream) {
    const float* x    = (const float*)d_in[0];
    const float* W_ih = (const float*)d_in[1];
    const float* W_hh = (const float*)d_in[2];
    const float* b_ih = (const float*)d_in[3];
    const float* b_hh = (const float*)d_in[4];
    const float* W_fc = (const float*)d_in[5];
    const float* b_fc = (const float*)d_in[6];
    float* out = (float*)d_out;

    // 4096 batch chains, one wave each: 1024 blocks x 256 threads (4 waves/block).
    rnn_fused_kernel<<<dim3(BATCH / 4), dim3(256), 0, stream>>>(
        x, W_ih, W_hh, b_ih, b_hh, W_fc, b_fc, out);
}

// Round 2
// 555.997 us; speedup vs baseline: 1.0147x; 1.0147x over previous
//
#include <hip/hip_runtime.h>

#define INPUT 32
#define HIDDEN 64
#define BATCH 4096
#define SEQ 256

__device__ __forceinline__ float readlane_f(float v, int l) {
    return __uint_as_float(__builtin_amdgcn_readlane(__float_as_uint(v), l));
}

// One wave (64 lanes) per batch chain. Lane j owns hidden unit j.
// Weights held in 24 NAMED float4 registers (96 VGPRs) — round-1's array
// version got rematerialized to in-loop global reloads (VGPR_Count=56, 435us).
// Named scalars + no t-unroll keep peak pressure ~110 < the (256,4) 128 cap.
__global__ __launch_bounds__(256, 4) void rnn_fused_kernel(
    const float* __restrict__ x,     // [B, T, 32]
    const float* __restrict__ W_ih,  // [64, 32]
    const float* __restrict__ W_hh,  // [64, 64]
    const float* __restrict__ b_ih,  // [64]
    const float* __restrict__ b_hh,  // [64]
    const float* __restrict__ W_fc,  // [1, 64]
    const float* __restrict__ b_fc,  // [1]
    float* __restrict__ out)         // [B, 1]
{
    const int lane = threadIdx.x & 63;
    int b = blockIdx.x * 4 + (threadIdx.x >> 6);
    b = __builtin_amdgcn_readfirstlane(b);  // uniform -> x loads scalarize

    // W_hh row `lane`: 16 float4 = 64 VGPRs, loaded once (L2-hot, 16KB total).
    const float4* __restrict__ wr = (const float4*)(W_hh + lane * HIDDEN);
    float4 W0 = wr[0],  W1 = wr[1],  W2 = wr[2],  W3 = wr[3];
    float4 W4 = wr[4],  W5 = wr[5],  W6 = wr[6],  W7 = wr[7];
    float4 W8 = wr[8],  W9 = wr[9],  W10 = wr[10], W11 = wr[11];
    float4 W12 = wr[12], W13 = wr[13], W14 = wr[14], W15 = wr[15];

    // W_ih row `lane`: 8 float4 = 32 VGPRs.
    const float4* __restrict__ vr = (const float4*)(W_ih + lane * INPUT);
    float4 V0 = vr[0], V1 = vr[1], V2 = vr[2], V3 = vr[3];
    float4 V4 = vr[4], V5 = vr[5], V6 = vr[6], V7 = vr[7];

    const float bias = b_ih[lane] + b_hh[lane];
    const float* __restrict__ xb = x + (size_t)b * SEQ * INPUT;

    float h = 0.0f;

#define IH(q) do { \
        a0 = fmaf(V##q.x, xt[4*q + 0], a0); \
        a1 = fmaf(V##q.y, xt[4*q + 1], a1); \
        a2 = fmaf(V##q.z, xt[4*q + 2], a2); \
        a3 = fmaf(V##q.w, xt[4*q + 3], a3); } while (0)

#define HH(q) do { \
        a0 = fmaf(W##q.x, readlane_f(h, 4*q + 0), a0); \
        a1 = fmaf(W##q.y, readlane_f(h, 4*q + 1), a1); \
        a2 = fmaf(W##q.z, readlane_f(h, 4*q + 2), a2); \
        a3 = fmaf(W##q.w, readlane_f(h, 4*q + 3), a3); } while (0)

#pragma unroll 1
    for (int t = 0; t < SEQ; ++t) {
        const float* __restrict__ xt = xb + t * INPUT;  // wave-uniform -> s_load

        float a0 = bias, a1 = 0.0f, a2 = 0.0f, a3 = 0.0f;

        // Input projection: x values wave-uniform (SMEM pipe), weights VGPR.
        IH(0); IH(1); IH(2); IH(3); IH(4); IH(5); IH(6); IH(7);

        // Recurrent matvec: h[k] broadcast via v_readlane (VALU pipe, no LDS).
        HH(0);  HH(1);  HH(2);  HH(3);  HH(4);  HH(5);  HH(6);  HH(7);
        HH(8);  HH(9);  HH(10); HH(11); HH(12); HH(13); HH(14); HH(15);

        float pre = (a0 + a1) + (a2 + a3);
        // tanh(p) = 1 - 2/(exp(2p)+1)
        float e = __expf(2.0f * pre);
        h = 1.0f - 2.0f * __builtin_amdgcn_rcpf(e + 1.0f);
    }
#undef IH
#undef HH

    // Head: out[b] = sum_j h[j]*W_fc[j] + b_fc (once per chain, cost ~0).
    float v = h * W_fc[lane];
#pragma unroll
    for (int off = 32; off > 0; off >>= 1) v += __shfl_xor(v, off, 64);
    if (lane == 0) out[b] = v + b_fc[0];
}

extern "C" void kernel_launch(void* const* d_in, const int* in_sizes, int n_in,
                              void* d_out, int out_size, void* d_ws, size_t ws_size,
                              hipStream_t stream) {
    const float* x    = (const float*)d_in[0];
    const float* W_ih = (const float*)d_in[1];
    const float* W_hh = (const float*)d_in[2];
    const float* b_ih = (const float*)d_in[3];
    const float* b_hh = (const float*)d_in[4];
    const float* W_fc = (const float*)d_in[5];
    const float* b_fc = (const float*)d_in[6];
    float* out = (float*)d_out;

    // 4096 batch chains, one wave each: 1024 blocks x 256 threads (4 waves/block).
    rnn_fused_kernel<<<dim3(BATCH / 4), dim3(256), 0, stream>>>(
        x, W_ih, W_hh, b_ih, b_hh, W_fc, b_fc, out);
}